// Round 2
// baseline (71.960 us; speedup 1.0000x reference)
//
#include <hip/hip_runtime.h>
#include <math.h>

#define THREADS 256
#define QBLOCKS 2048

// ---- codebook: fp32 levels exactly as numpy float32 computes them ----
static constexpr float kLvl[16] = {
    0.0f      / 0.75f, 0.015625f / 0.75f, 0.03125f / 0.75f, 0.046875f / 0.75f,
    0.0625f   / 0.75f, 0.09375f  / 0.75f, 0.125f   / 0.75f, 0.140625f / 0.75f,
    0.1875f   / 0.75f, 0.25f     / 0.75f, 0.28125f / 0.75f, 0.375f    / 0.75f,
    0.5f      / 0.75f, 0.515625f / 0.75f, 0.5625f  / 0.75f, 0.75f     / 0.75f,
};
// exact f64 midpoints of adjacent f32 levels: strict a>mid == numpy f32 argmin (Sterbenz)
static constexpr double kMid[15] = {
    ((double)kLvl[0]  + (double)kLvl[1])  * 0.5, ((double)kLvl[1]  + (double)kLvl[2])  * 0.5,
    ((double)kLvl[2]  + (double)kLvl[3])  * 0.5, ((double)kLvl[3]  + (double)kLvl[4])  * 0.5,
    ((double)kLvl[4]  + (double)kLvl[5])  * 0.5, ((double)kLvl[5]  + (double)kLvl[6])  * 0.5,
    ((double)kLvl[6]  + (double)kLvl[7])  * 0.5, ((double)kLvl[7]  + (double)kLvl[8])  * 0.5,
    ((double)kLvl[8]  + (double)kLvl[9])  * 0.5, ((double)kLvl[9]  + (double)kLvl[10]) * 0.5,
    ((double)kLvl[10] + (double)kLvl[11]) * 0.5, ((double)kLvl[11] + (double)kLvl[12]) * 0.5,
    ((double)kLvl[12] + (double)kLvl[13]) * 0.5, ((double)kLvl[13] + (double)kLvl[14]) * 0.5,
    ((double)kLvl[14] + (double)kLvl[15]) * 0.5,
};

// complete-binary-tree sum over 64 lanes (f32 add is commutative -> xor butterfly
// reproduces numpy's adjacent-pair tree exactly)
__device__ __forceinline__ float tree64(float v) {
    #pragma unroll
    for (int m = 1; m <= 32; m <<= 1)
        v += __shfl_xor(v, m, 64);
    return v;
}

// One thread = one numpy pairwise leaf (128 elems, 8 accumulators, stride 8).
// One block = 256 contiguous leaves; block output is an exact complete-tree node.
// PASS 0: sum(w).  PASS 1: sum((w - mean)^2), mean read from params[0].
template<int PASS>
__global__ __launch_bounds__(THREADS) void leaf_sum(const float* __restrict__ w,
                                                    float* __restrict__ bout,
                                                    const float* __restrict__ params) {
    #pragma clang fp contract(off)
    const float mean = (PASS == 1) ? params[0] : 0.0f;
    const long long leaf = (long long)blockIdx.x * THREADS + threadIdx.x;
    const float4* p = (const float4*)(w + (leaf << 7));
    float r0, r1, r2, r3, r4, r5, r6, r7;
    {
        float4 va = p[0], vb = p[1];
        if (PASS == 1) {
            float t;
            t = va.x - mean; r0 = t * t;
            t = va.y - mean; r1 = t * t;
            t = va.z - mean; r2 = t * t;
            t = va.w - mean; r3 = t * t;
            t = vb.x - mean; r4 = t * t;
            t = vb.y - mean; r5 = t * t;
            t = vb.z - mean; r6 = t * t;
            t = vb.w - mean; r7 = t * t;
        } else {
            r0 = va.x; r1 = va.y; r2 = va.z; r3 = va.w;
            r4 = vb.x; r5 = vb.y; r6 = vb.z; r7 = vb.w;
        }
    }
    #pragma unroll
    for (int i = 1; i < 16; ++i) {
        float4 va = p[2 * i], vb = p[2 * i + 1];
        if (PASS == 1) {
            float t;
            t = va.x - mean; r0 += t * t;
            t = va.y - mean; r1 += t * t;
            t = va.z - mean; r2 += t * t;
            t = va.w - mean; r3 += t * t;
            t = vb.x - mean; r4 += t * t;
            t = vb.y - mean; r5 += t * t;
            t = vb.z - mean; r6 += t * t;
            t = vb.w - mean; r7 += t * t;
        } else {
            r0 += va.x; r1 += va.y; r2 += va.z; r3 += va.w;
            r4 += vb.x; r5 += vb.y; r6 += vb.z; r7 += vb.w;
        }
    }
    float res = ((r0 + r1) + (r2 + r3)) + ((r4 + r5) + (r6 + r7));  // numpy leaf combine
    res = tree64(res);                                              // tree over 64 leaves
    __shared__ float ws4[THREADS / 64];
    if ((threadIdx.x & 63) == 0) ws4[threadIdx.x >> 6] = res;
    __syncthreads();
    if (threadIdx.x == 0)
        bout[blockIdx.x] = (ws4[0] + ws4[1]) + (ws4[2] + ws4[3]);   // tree over 256 leaves
}

// Combine 512 block partials with the exact complete tree; finish stats.
template<int PASS>
__global__ __launch_bounds__(THREADS) void finalize(const float* __restrict__ bout, int nb,
                                                    const float* __restrict__ alpha_ptr,
                                                    long long n, float* __restrict__ params) {
    #pragma clang fp contract(off)
    float v = 0.0f;
    int i0 = 2 * threadIdx.x;
    if (i0 + 1 < nb)      v = bout[i0] + bout[i0 + 1];   // level-1 adjacent pairs
    else if (i0 < nb)     v = bout[i0];
    v = tree64(v);
    __shared__ float ws4[THREADS / 64];
    if ((threadIdx.x & 63) == 0) ws4[threadIdx.x >> 6] = v;
    __syncthreads();
    if (threadIdx.x == 0) {
        float total = (ws4[0] + ws4[1]) + (ws4[2] + ws4[3]);
        if (PASS == 0) {
            params[0] = total / (float)n;                 // mean (exact: n = 2^24)
        } else {
            float var = total / (float)(n - 1);           // f32 IEEE divide, ddof=1
            params[1] = sqrtf(var);                       // correctly-rounded f32 sqrt
            params[2] = alpha_ptr[0];
        }
    }
}

__device__ __forceinline__ float q1(float wv, float mean, float sd, float alpha,
                                    const float* __restrict__ slvl) {
    float wn = (wv - mean) / sd;    // f32 IEEE
    float x  = wn / alpha;          // f32 IEEE
    float xc = fminf(fmaxf(x, -1.0f), 1.0f);
    float a  = fabsf(xc);
    double ad = (double)a;
    int idx = 0;
    #pragma unroll
    for (int i = 0; i < 15; ++i) idx += (ad > kMid[i]) ? 1 : 0;  // exact midpoint compare
    float o = slvl[idx] * alpha;
    return (xc < 0.0f) ? -o : o;
}

__global__ __launch_bounds__(THREADS) void quantize(const float4* __restrict__ w4,
                                                    float4* __restrict__ o4,
                                                    long long n4,
                                                    const float* __restrict__ params) {
    #pragma clang fp contract(off)
    __shared__ float slvl[16];
    if (threadIdx.x < 16) slvl[threadIdx.x] = kLvl[threadIdx.x];
    __syncthreads();
    const float mean = params[0], sd = params[1], alpha = params[2];
    long long tid    = (long long)blockIdx.x * blockDim.x + threadIdx.x;
    long long stride = (long long)gridDim.x * blockDim.x;
    for (long long i = tid; i < n4; i += stride) {
        float4 v = w4[i], r;
        r.x = q1(v.x, mean, sd, alpha, slvl);
        r.y = q1(v.y, mean, sd, alpha, slvl);
        r.z = q1(v.z, mean, sd, alpha, slvl);
        r.w = q1(v.w, mean, sd, alpha, slvl);
        o4[i] = r;
    }
}

extern "C" void kernel_launch(void* const* d_in, const int* in_sizes, int n_in,
                              void* d_out, int out_size, void* d_ws, size_t ws_size,
                              hipStream_t stream) {
    const float* w     = (const float*)d_in[0];
    const float* alpha = (const float*)d_in[1];
    long long n = (long long)in_sizes[0];          // 16777216 = 2^24

    int nblk = (int)(n >> 15);                     // n / (128 elems * 256 leaves) = 512
    float* bout   = (float*)d_ws;                  // 512 f32 partials
    float* params = bout + 1024;                   // [mean, std, alpha]

    leaf_sum<0><<<nblk, THREADS, 0, stream>>>(w, bout, params);
    finalize<0><<<1, THREADS, 0, stream>>>(bout, nblk, alpha, n, params);
    leaf_sum<1><<<nblk, THREADS, 0, stream>>>(w, bout, params);
    finalize<1><<<1, THREADS, 0, stream>>>(bout, nblk, alpha, n, params);
    quantize<<<QBLOCKS, THREADS, 0, stream>>>((const float4*)w, (float4*)d_out, n >> 2, params);
}

// Round 3
// 66.935 us; speedup vs baseline: 1.0751x; 1.0751x over previous
//
#include <hip/hip_runtime.h>
#include <math.h>

#define THREADS 256
#define QBLOCKS 2048

// params layout (floats in d_ws after the 512 block partials)
#define P_MEAN  0
#define P_SD    1
#define P_ALPHA 2
#define P_THR   3    // 15 u-space thresholds
#define P_OLVL  18   // 16 output levels (level * alpha)
#define P_COUNT 34

// ---- codebook: fp32 levels exactly as numpy float32 computes them ----
static constexpr float kLvl[16] = {
    0.0f      / 0.75f, 0.015625f / 0.75f, 0.03125f / 0.75f, 0.046875f / 0.75f,
    0.0625f   / 0.75f, 0.09375f  / 0.75f, 0.125f   / 0.75f, 0.140625f / 0.75f,
    0.1875f   / 0.75f, 0.25f     / 0.75f, 0.28125f / 0.75f, 0.375f    / 0.75f,
    0.5f      / 0.75f, 0.515625f / 0.75f, 0.5625f  / 0.75f, 0.75f     / 0.75f,
};
// exact f64 midpoints of adjacent f32 levels: strict a>mid == numpy f32 argmin (Sterbenz)
static constexpr double kMid[15] = {
    ((double)kLvl[0]  + (double)kLvl[1])  * 0.5, ((double)kLvl[1]  + (double)kLvl[2])  * 0.5,
    ((double)kLvl[2]  + (double)kLvl[3])  * 0.5, ((double)kLvl[3]  + (double)kLvl[4])  * 0.5,
    ((double)kLvl[4]  + (double)kLvl[5])  * 0.5, ((double)kLvl[5]  + (double)kLvl[6])  * 0.5,
    ((double)kLvl[6]  + (double)kLvl[7])  * 0.5, ((double)kLvl[7]  + (double)kLvl[8])  * 0.5,
    ((double)kLvl[8]  + (double)kLvl[9])  * 0.5, ((double)kLvl[9]  + (double)kLvl[10]) * 0.5,
    ((double)kLvl[10] + (double)kLvl[11]) * 0.5, ((double)kLvl[11] + (double)kLvl[12]) * 0.5,
    ((double)kLvl[12] + (double)kLvl[13]) * 0.5, ((double)kLvl[13] + (double)kLvl[14]) * 0.5,
    ((double)kLvl[14] + (double)kLvl[15]) * 0.5,
};

// complete-binary-tree sum over 64 lanes (f32 add is commutative -> xor butterfly
// reproduces numpy's adjacent-pair tree exactly)
__device__ __forceinline__ float tree64(float v) {
    #pragma unroll
    for (int m = 1; m <= 32; m <<= 1)
        v += __shfl_xor(v, m, 64);
    return v;
}

// One thread = one numpy pairwise leaf (128 elems, 8 accumulators, stride 8).
// One block = 256 contiguous leaves; block output is an exact complete-tree node.
// PASS 0: sum(w).  PASS 1: sum((w - mean)^2), mean read from params[P_MEAN].
template<int PASS>
__global__ __launch_bounds__(THREADS) void leaf_sum(const float* __restrict__ w,
                                                    float* __restrict__ bout,
                                                    const float* __restrict__ params) {
    #pragma clang fp contract(off)
    const float mean = (PASS == 1) ? params[P_MEAN] : 0.0f;
    const long long leaf = (long long)blockIdx.x * THREADS + threadIdx.x;
    const float4* p = (const float4*)(w + (leaf << 7));
    float r0, r1, r2, r3, r4, r5, r6, r7;
    {
        float4 va = p[0], vb = p[1];
        if (PASS == 1) {
            float t;
            t = va.x - mean; r0 = t * t;
            t = va.y - mean; r1 = t * t;
            t = va.z - mean; r2 = t * t;
            t = va.w - mean; r3 = t * t;
            t = vb.x - mean; r4 = t * t;
            t = vb.y - mean; r5 = t * t;
            t = vb.z - mean; r6 = t * t;
            t = vb.w - mean; r7 = t * t;
        } else {
            r0 = va.x; r1 = va.y; r2 = va.z; r3 = va.w;
            r4 = vb.x; r5 = vb.y; r6 = vb.z; r7 = vb.w;
        }
    }
    #pragma unroll
    for (int i = 1; i < 16; ++i) {
        float4 va = p[2 * i], vb = p[2 * i + 1];
        if (PASS == 1) {
            float t;
            t = va.x - mean; r0 += t * t;
            t = va.y - mean; r1 += t * t;
            t = va.z - mean; r2 += t * t;
            t = va.w - mean; r3 += t * t;
            t = vb.x - mean; r4 += t * t;
            t = vb.y - mean; r5 += t * t;
            t = vb.z - mean; r6 += t * t;
            t = vb.w - mean; r7 += t * t;
        } else {
            r0 += va.x; r1 += va.y; r2 += va.z; r3 += va.w;
            r4 += vb.x; r5 += vb.y; r6 += vb.z; r7 += vb.w;
        }
    }
    float res = ((r0 + r1) + (r2 + r3)) + ((r4 + r5) + (r6 + r7));  // numpy leaf combine
    res = tree64(res);                                              // tree over 64 leaves
    __shared__ float ws4[THREADS / 64];
    if ((threadIdx.x & 63) == 0) ws4[threadIdx.x >> 6] = res;
    __syncthreads();
    if (threadIdx.x == 0)
        bout[blockIdx.x] = (ws4[0] + ws4[1]) + (ws4[2] + ws4[3]);   // tree over 256 leaves
}

// Combine 512 block partials with the exact complete tree; finish stats.
// PASS 1 additionally precomputes the 15 u-space decision thresholds (exact
// pullback of the IEEE f32 chain u/sd -> /alpha -> clip -> midpoint compare,
// via monotone binary search over f32 bit patterns) and the 16 output levels.
template<int PASS>
__global__ __launch_bounds__(THREADS) void finalize(const float* __restrict__ bout, int nb,
                                                    const float* __restrict__ alpha_ptr,
                                                    long long n, float* __restrict__ params) {
    #pragma clang fp contract(off)
    float v = 0.0f;
    int i0 = 2 * threadIdx.x;
    if (i0 + 1 < nb)      v = bout[i0] + bout[i0 + 1];   // level-1 adjacent pairs
    else if (i0 < nb)     v = bout[i0];
    v = tree64(v);
    __shared__ float ws4[THREADS / 64];
    __shared__ float s_sd, s_alpha;
    if ((threadIdx.x & 63) == 0) ws4[threadIdx.x >> 6] = v;
    __syncthreads();
    if (threadIdx.x == 0) {
        float total = (ws4[0] + ws4[1]) + (ws4[2] + ws4[3]);
        if (PASS == 0) {
            params[P_MEAN] = total / (float)n;            // mean (exact: n = 2^24)
        } else {
            float var = total / (float)(n - 1);           // f32 IEEE divide, ddof=1
            float sd  = sqrtf(var);                       // correctly-rounded f32 sqrt
            float al  = alpha_ptr[0];
            params[P_SD]    = sd;
            params[P_ALPHA] = al;
            s_sd = sd; s_alpha = al;
        }
    }
    if (PASS == 1) {
        __syncthreads();
        const float sd = s_sd, al = s_alpha;
        if (threadIdx.x < 15) {
            // smallest f32 u >= 0 whose exact chain value exceeds kMid[i]
            const double mid = kMid[threadIdx.x];
            unsigned lo = 0u, hi = 0x7F7FFFFFu;           // [+0, max finite]
            while (lo < hi) {
                unsigned m = (lo + hi) >> 1;
                float u  = __uint_as_float(m);
                float y  = u / sd;                        // f32 IEEE div (matches numpy)
                float x  = y / al;                        // f32 IEEE div
                float xc = fminf(x, 1.0f);                // clip (abs domain: upper only)
                if ((double)xc > mid) hi = m; else lo = m + 1;
            }
            params[P_THR + threadIdx.x] = __uint_as_float(lo);
        }
        if (threadIdx.x >= 16 && threadIdx.x < 32) {
            int i = threadIdx.x - 16;
            params[P_OLVL + i] = kLvl[i] * al;            // f32 mul: same bits as ref path
        }
    }
}

// ---- quantize: no divides, no f64 — pure f32 threshold compares ----
__global__ __launch_bounds__(THREADS) void quantize(const float4* __restrict__ w4,
                                                    float4* __restrict__ o4,
                                                    long long n4,
                                                    const float* __restrict__ params) {
    #pragma clang fp contract(off)
    __shared__ float so[16];
    if (threadIdx.x < 16) so[threadIdx.x] = params[P_OLVL + threadIdx.x];
    __syncthreads();
    const float mean = params[P_MEAN];
    float T[15];
    #pragma unroll
    for (int i = 0; i < 15; ++i) T[i] = params[P_THR + i];   // uniform -> SGPRs

    long long tid    = (long long)blockIdx.x * blockDim.x + threadIdx.x;
    long long stride = (long long)gridDim.x * blockDim.x;
    for (long long i = tid; i < n4; i += stride) {
        float4 v = w4[i], r;
        {
            float u = v.x - mean; float au = fabsf(u);
            int idx = 0;
            #pragma unroll
            for (int k = 0; k < 15; ++k) idx += (au >= T[k]) ? 1 : 0;
            r.x = copysignf(so[idx], u);
        }
        {
            float u = v.y - mean; float au = fabsf(u);
            int idx = 0;
            #pragma unroll
            for (int k = 0; k < 15; ++k) idx += (au >= T[k]) ? 1 : 0;
            r.y = copysignf(so[idx], u);
        }
        {
            float u = v.z - mean; float au = fabsf(u);
            int idx = 0;
            #pragma unroll
            for (int k = 0; k < 15; ++k) idx += (au >= T[k]) ? 1 : 0;
            r.z = copysignf(so[idx], u);
        }
        {
            float u = v.w - mean; float au = fabsf(u);
            int idx = 0;
            #pragma unroll
            for (int k = 0; k < 15; ++k) idx += (au >= T[k]) ? 1 : 0;
            r.w = copysignf(so[idx], u);
        }
        o4[i] = r;
    }
}

extern "C" void kernel_launch(void* const* d_in, const int* in_sizes, int n_in,
                              void* d_out, int out_size, void* d_ws, size_t ws_size,
                              hipStream_t stream) {
    const float* w     = (const float*)d_in[0];
    const float* alpha = (const float*)d_in[1];
    long long n = (long long)in_sizes[0];          // 16777216 = 2^24

    int nblk = (int)(n >> 15);                     // n / (128 elems * 256 leaves) = 512
    float* bout   = (float*)d_ws;                  // 512 f32 partials
    float* params = bout + 1024;                   // P_COUNT floats

    leaf_sum<0><<<nblk, THREADS, 0, stream>>>(w, bout, params);
    finalize<0><<<1, THREADS, 0, stream>>>(bout, nblk, alpha, n, params);
    leaf_sum<1><<<nblk, THREADS, 0, stream>>>(w, bout, params);
    finalize<1><<<1, THREADS, 0, stream>>>(bout, nblk, alpha, n, params);
    quantize<<<QBLOCKS, THREADS, 0, stream>>>((const float4*)w, (float4*)d_out, n >> 2, params);
}

// Round 4
// 61.618 us; speedup vs baseline: 1.1678x; 1.0863x over previous
//
#include <hip/hip_runtime.h>
#include <math.h>

#define THREADS 256

typedef float f2v __attribute__((ext_vector_type(2)));
typedef float f4v __attribute__((ext_vector_type(4)));

// ---- codebook: fp32 levels exactly as numpy float32 computes them ----
static constexpr float kLvl[16] = {
    0.0f      / 0.75f, 0.015625f / 0.75f, 0.03125f / 0.75f, 0.046875f / 0.75f,
    0.0625f   / 0.75f, 0.09375f  / 0.75f, 0.125f   / 0.75f, 0.140625f / 0.75f,
    0.1875f   / 0.75f, 0.25f     / 0.75f, 0.28125f / 0.75f, 0.375f    / 0.75f,
    0.5f      / 0.75f, 0.515625f / 0.75f, 0.5625f  / 0.75f, 0.75f     / 0.75f,
};
// exact f64 midpoints of adjacent f32 levels: strict a>mid == numpy f32 argmin (Sterbenz)
static constexpr double kMid[15] = {
    ((double)kLvl[0]  + (double)kLvl[1])  * 0.5, ((double)kLvl[1]  + (double)kLvl[2])  * 0.5,
    ((double)kLvl[2]  + (double)kLvl[3])  * 0.5, ((double)kLvl[3]  + (double)kLvl[4])  * 0.5,
    ((double)kLvl[4]  + (double)kLvl[5])  * 0.5, ((double)kLvl[5]  + (double)kLvl[6])  * 0.5,
    ((double)kLvl[6]  + (double)kLvl[7])  * 0.5, ((double)kLvl[7]  + (double)kLvl[8])  * 0.5,
    ((double)kLvl[8]  + (double)kLvl[9])  * 0.5, ((double)kLvl[9]  + (double)kLvl[10]) * 0.5,
    ((double)kLvl[10] + (double)kLvl[11]) * 0.5, ((double)kLvl[11] + (double)kLvl[12]) * 0.5,
    ((double)kLvl[12] + (double)kLvl[13]) * 0.5, ((double)kLvl[13] + (double)kLvl[14]) * 0.5,
    ((double)kLvl[14] + (double)kLvl[15]) * 0.5,
};

// complete-binary-tree sum over 64 lanes (f32 add commutative -> xor butterfly
// reproduces numpy's adjacent-pair tree exactly)
__device__ __forceinline__ float tree64(float v) {
    #pragma unroll
    for (int m = 1; m <= 32; m <<= 1)
        v += __shfl_xor(v, m, 64);
    return v;
}

// ---- leaf pass, coalesced lane map: 4 lanes per 128-elem numpy leaf.
// Lane r of a leaf owns accumulators {2r, 2r+1} (float2 load per t-step,
// serial t order per acc == numpy). acc.x+acc.y == numpy's (r_{2r}+r_{2r+1});
// xor1,2 finish the in-leaf tree, xor4..32 the 16-leaf adjacent tree. Exact.
// Block = 64 leaves = 8192 elems.  PASS 0: sum(w).  PASS 1: sum((w-mean)^2),
// mean recomputed per-block from PASS-0 partials (kernel boundary = coherent).
template<int PASS>
__global__ __launch_bounds__(THREADS) void leaf_pass(const float* __restrict__ w,
                                                     const float* __restrict__ bprev,
                                                     float* __restrict__ bout,
                                                     long long n, int nb) {
    #pragma clang fp contract(off)
    __shared__ float ws4[4];
    __shared__ float smean;
    float mean = 0.0f;
    if (PASS == 1) {
        // prologue: exact complete-tree reduce of nb partials -> mean
        int i0 = threadIdx.x * 8;
        float v = 0.0f;
        if (i0 + 7 < nb) {
            const float* p = bprev + i0;
            v = ((p[0] + p[1]) + (p[2] + p[3])) + ((p[4] + p[5]) + (p[6] + p[7]));
        }
        v = tree64(v);
        if ((threadIdx.x & 63) == 0) ws4[threadIdx.x >> 6] = v;
        __syncthreads();
        if (threadIdx.x == 0)
            smean = ((ws4[0] + ws4[1]) + (ws4[2] + ws4[3])) / (float)n;
        __syncthreads();
        mean = smean;
    }

    const long long base = (long long)blockIdx.x * 8192
                         + (long long)(threadIdx.x >> 2) * 128
                         + (long long)(threadIdx.x & 3) * 2;
    const f2v* p = (const f2v*)(w + base);
    float s0, s1;
    {
        f2v a = p[0];
        if (PASS == 1) { float x = a.x - mean, y = a.y - mean; s0 = x * x; s1 = y * y; }
        else           { s0 = a.x; s1 = a.y; }
    }
    #pragma unroll
    for (int t = 1; t < 16; ++t) {
        f2v a = p[4 * t];                       // +32 bytes per t-step
        if (PASS == 1) { float x = a.x - mean, y = a.y - mean; s0 += x * x; s1 += y * y; }
        else           { s0 += a.x; s1 += a.y; }
    }
    float s = s0 + s1;                          // numpy pair (r_{2r}+r_{2r+1})
    s = tree64(s);                              // in-leaf tree + 16-leaf tree
    if ((threadIdx.x & 63) == 0) ws4[threadIdx.x >> 6] = s;
    __syncthreads();
    if (threadIdx.x == 0)
        bout[blockIdx.x] = (ws4[0] + ws4[1]) + (ws4[2] + ws4[3]);   // 64-leaf node
}

// ---- quantize with fused finalize: per-block recompute mean/sd from partials,
// pull the 15 decision boundaries back into u = (w-mean) space via monotone
// binary search over f32 bit patterns (bit-exact vs the IEEE f32 chain), then
// stream: 1 sub + 1 abs + 15 sgpr-ish cmps + LDS lookup + copysign per elem.
__global__ __launch_bounds__(THREADS) void quantize_k(const f4v* __restrict__ w4,
                                                      f4v* __restrict__ o4,
                                                      const float* __restrict__ bout0,
                                                      const float* __restrict__ bout1,
                                                      const float* __restrict__ alpha_ptr,
                                                      long long n, int nb) {
    #pragma clang fp contract(off)
    __shared__ float wsA[4], wsB[4];
    __shared__ float sMean, sSd;
    __shared__ float sT[15];
    __shared__ float sO[16];
    {
        int i0 = threadIdx.x * 8;
        float v = 0.0f, u = 0.0f;
        if (i0 + 7 < nb) {
            const float* p0 = bout0 + i0;
            const float* p1 = bout1 + i0;
            v = ((p0[0] + p0[1]) + (p0[2] + p0[3])) + ((p0[4] + p0[5]) + (p0[6] + p0[7]));
            u = ((p1[0] + p1[1]) + (p1[2] + p1[3])) + ((p1[4] + p1[5]) + (p1[6] + p1[7]));
        }
        v = tree64(v);
        u = tree64(u);
        if ((threadIdx.x & 63) == 0) { wsA[threadIdx.x >> 6] = v; wsB[threadIdx.x >> 6] = u; }
        __syncthreads();
        if (threadIdx.x == 0) {
            float tv = (wsA[0] + wsA[1]) + (wsA[2] + wsA[3]);
            float tu = (wsB[0] + wsB[1]) + (wsB[2] + wsB[3]);
            sMean = tv / (float)n;                 // exact semantics of ref (f32)
            sSd   = sqrtf(tu / (float)(n - 1));    // f32 IEEE div + sqrt, ddof=1
        }
        __syncthreads();
    }
    const float sd = sSd;
    const float al = alpha_ptr[0];
    if (threadIdx.x < 15) {
        // smallest f32 u >= 0 whose IEEE f32 chain value exceeds kMid[i]
        const double mid = kMid[threadIdx.x];
        unsigned lo = 0u, hi = 0x7F800000u;        // [+0, +inf]; chain(inf)=inf>mid
        while (lo < hi) {
            unsigned m = (lo + hi) >> 1;
            float uu = __uint_as_float(m);
            float y  = uu / sd;                    // f32 IEEE div (matches numpy)
            float x  = y / al;                     // f32 IEEE div
            float xc = fminf(x, 1.0f);             // clip upper (abs domain)
            if ((double)xc > mid) hi = m; else lo = m + 1;
        }
        sT[threadIdx.x] = __uint_as_float(lo);
    } else if (threadIdx.x < 31) {
        int i = threadIdx.x - 15;
        sO[i] = kLvl[i] * al;                      // same bits as ref's level*alpha
    } else if (threadIdx.x == 31) {
        sO[0] = 0.0f;
    }
    __syncthreads();

    const float mean = sMean;
    float T[15];
    #pragma unroll
    for (int k = 0; k < 15; ++k) T[k] = sT[k];

    long long n4     = n >> 2;
    long long tid    = (long long)blockIdx.x * THREADS + threadIdx.x;
    long long stride = (long long)gridDim.x * THREADS;

    long long i = tid;
    for (; i + stride < n4; i += 2 * stride) {     // unroll-2: two f4v in flight
        f4v a = __builtin_nontemporal_load(&w4[i]);
        f4v b = __builtin_nontemporal_load(&w4[i + stride]);
        f4v ra, rb;
        {
            float uu, au; int idx;
            uu = a.x - mean; au = fabsf(uu); idx = 0;
            #pragma unroll
            for (int k = 0; k < 15; ++k) idx += (au >= T[k]) ? 1 : 0;
            ra.x = copysignf(sO[idx], uu);
            uu = a.y - mean; au = fabsf(uu); idx = 0;
            #pragma unroll
            for (int k = 0; k < 15; ++k) idx += (au >= T[k]) ? 1 : 0;
            ra.y = copysignf(sO[idx], uu);
            uu = a.z - mean; au = fabsf(uu); idx = 0;
            #pragma unroll
            for (int k = 0; k < 15; ++k) idx += (au >= T[k]) ? 1 : 0;
            ra.z = copysignf(sO[idx], uu);
            uu = a.w - mean; au = fabsf(uu); idx = 0;
            #pragma unroll
            for (int k = 0; k < 15; ++k) idx += (au >= T[k]) ? 1 : 0;
            ra.w = copysignf(sO[idx], uu);
            uu = b.x - mean; au = fabsf(uu); idx = 0;
            #pragma unroll
            for (int k = 0; k < 15; ++k) idx += (au >= T[k]) ? 1 : 0;
            rb.x = copysignf(sO[idx], uu);
            uu = b.y - mean; au = fabsf(uu); idx = 0;
            #pragma unroll
            for (int k = 0; k < 15; ++k) idx += (au >= T[k]) ? 1 : 0;
            rb.y = copysignf(sO[idx], uu);
            uu = b.z - mean; au = fabsf(uu); idx = 0;
            #pragma unroll
            for (int k = 0; k < 15; ++k) idx += (au >= T[k]) ? 1 : 0;
            rb.z = copysignf(sO[idx], uu);
            uu = b.w - mean; au = fabsf(uu); idx = 0;
            #pragma unroll
            for (int k = 0; k < 15; ++k) idx += (au >= T[k]) ? 1 : 0;
            rb.w = copysignf(sO[idx], uu);
        }
        __builtin_nontemporal_store(ra, &o4[i]);
        __builtin_nontemporal_store(rb, &o4[i + stride]);
    }
    for (; i < n4; i += stride) {                  // tail (unused at n = 2^24)
        f4v a = __builtin_nontemporal_load(&w4[i]);
        f4v ra;
        float uu, au; int idx;
        uu = a.x - mean; au = fabsf(uu); idx = 0;
        #pragma unroll
        for (int k = 0; k < 15; ++k) idx += (au >= T[k]) ? 1 : 0;
        ra.x = copysignf(sO[idx], uu);
        uu = a.y - mean; au = fabsf(uu); idx = 0;
        #pragma unroll
        for (int k = 0; k < 15; ++k) idx += (au >= T[k]) ? 1 : 0;
        ra.y = copysignf(sO[idx], uu);
        uu = a.z - mean; au = fabsf(uu); idx = 0;
        #pragma unroll
        for (int k = 0; k < 15; ++k) idx += (au >= T[k]) ? 1 : 0;
        ra.z = copysignf(sO[idx], uu);
        uu = a.w - mean; au = fabsf(uu); idx = 0;
        #pragma unroll
        for (int k = 0; k < 15; ++k) idx += (au >= T[k]) ? 1 : 0;
        ra.w = copysignf(sO[idx], uu);
        __builtin_nontemporal_store(ra, &o4[i]);
    }
}

extern "C" void kernel_launch(void* const* d_in, const int* in_sizes, int n_in,
                              void* d_out, int out_size, void* d_ws, size_t ws_size,
                              hipStream_t stream) {
    const float* w     = (const float*)d_in[0];
    const float* alpha = (const float*)d_in[1];
    float* out = (float*)d_out;
    long long n = (long long)in_sizes[0];          // 16777216 = 2^24

    int nblk = (int)(n >> 13);                     // 8192 elems/block -> 2048 blocks
    float* bout0 = (float*)d_ws;                   // nblk partials (sum)
    float* bout1 = bout0 + nblk;                   // nblk partials (sumsq)

    leaf_pass<0><<<nblk, THREADS, 0, stream>>>(w, nullptr, bout0, n, nblk);
    leaf_pass<1><<<nblk, THREADS, 0, stream>>>(w, bout0, bout1, n, nblk);
    quantize_k<<<2048, THREADS, 0, stream>>>((const f4v*)w, (f4v*)out,
                                             bout0, bout1, alpha, n, nblk);
}